// Round 8
// baseline (78.881 us; speedup 1.0000x reference)
//
#include <hip/hip_runtime.h>

typedef __attribute__((ext_vector_type(8))) short short8v;
typedef __attribute__((ext_vector_type(4))) short short4v;
typedef __attribute__((ext_vector_type(4))) float float4v;

// fp32 -> bf16 via native cast: compiler emits v_cvt_pk_bf16_f32 (RNE).
__device__ __forceinline__ short f2bf(float f) {
  __bf16 h = (__bf16)f;
  return __builtin_bit_cast(short, h);
}

__device__ __forceinline__ short8v cvt8(float4 a, float4 b) {
  short8v r;
  r[0] = f2bf(a.x); r[1] = f2bf(a.y); r[2] = f2bf(a.z); r[3] = f2bf(a.w);
  r[4] = f2bf(b.x); r[5] = f2bf(b.y); r[6] = f2bf(b.z); r[7] = f2bf(b.w);
  return r;
}

// Stage a 64x64 f32 matrix into LDS as bf16, XOR-swizzled:
// element (r, col) -> dst[r*64 + (col ^ ((r&7)<<3))].
__device__ __forceinline__ void stage_weight(const float* __restrict__ src,
                                             short* __restrict__ dst, int tid) {
  const int r = tid >> 2;
  const int c0 = (tid & 3) << 4;
  const float* p = src + r * 64 + c0;
  float4 f0 = reinterpret_cast<const float4*>(p)[0];
  float4 f1 = reinterpret_cast<const float4*>(p)[1];
  float4 f2 = reinterpret_cast<const float4*>(p)[2];
  float4 f3 = reinterpret_cast<const float4*>(p)[3];
  short8v g0 = cvt8(f0, f1), g1 = cvt8(f2, f3);
  const int sw = (r & 7) << 3;
  *reinterpret_cast<short8v*>(&dst[r * 64 + ((c0)     ^ sw)]) = g0;
  *reinterpret_cast<short8v*>(&dst[r * 64 + ((c0 + 8) ^ sw)]) = g1;
}

constexpr int ROWS = 4;  // rows of x per wave; grid = 8192/(4*ROWS) = 512

// MLP-pipelined version (R7 post-mortem: occupancy flat 26->36% with no time
// delta; effective BW 3.5/6.3 TB/s => in-flight-limited). Two 8-load half-row
// register buffers rotate with prefetch distance 2 halves (= 1 row): consume
// half H, MFMA it, re-issue H+2 into the freed buffer. During stage-2 the
// next row's 16 dwordx4 stay outstanding. No lgkmcnt fences: their "memory"
// clobber would pin the prefetch loads; y1 write->read ordering is already
// guaranteed by the per-wave in-order DS pipe + may-alias compiler ordering.
__global__ __launch_bounds__(256, 2)
void kron64_kernel(const float* __restrict__ x, const float* __restrict__ A,
                   const float* __restrict__ B, const float* __restrict__ bias,
                   float* __restrict__ out) {
  __shared__ short bw[4096];     // B bf16 [64][64] swizzled, 8 KB
  __shared__ short aw[4096];     // A bf16 [64][64] swizzled, 8 KB
  __shared__ short y1[4][4096];  // per-wave Y1^T, 32 KB

  const int tid = threadIdx.x;
  const int w = tid >> 6;
  const int lane = tid & 63;
  const int g = lane >> 4;       // lane group 0..3
  const int c = lane & 15;       // lane-in-group 0..15
  const int swz = (c & 7) << 3;  // element-index XOR swizzle (row&7 == c&7)

  stage_weight(B, bw, tid);
  stage_weight(A, aw, tid);
  __syncthreads();

  const int m0 = (blockIdx.x * 4 + w) * ROWS;
  const float* xm = x + (size_t)m0 * 4096;
  short* yw = y1[w];
  const float4v vzero = {0.f, 0.f, 0.f, 0.f};

  // Persistent B fragments: frag(qt,kk)[i] = B[16qt+c][32kk+8g+i]
  short8v bfr[4][2];
#pragma unroll
  for (int qt = 0; qt < 4; ++qt)
#pragma unroll
    for (int kk = 0; kk < 2; ++kk)
      bfr[qt][kk] = *reinterpret_cast<const short8v*>(
          &bw[(16 * qt + c) * 64 + ((32 * kk + 8 * g) ^ swz)]);

  float4 xa[8], xb[8];  // two half-row buffers, 32 VGPR each

  // Half H (= 2*row + h) covers at in {2h, 2h+1}: 8 dwordx4 per buffer.
  auto issue = [&](float4* buf, int H) {
    const float* p0 =
        xm + (size_t)(H >> 1) * 4096 + ((H & 1) * 32 + c) * 64 + 8 * g;
#pragma unroll
    for (int atl = 0; atl < 2; ++atl)
#pragma unroll
      for (int kk = 0; kk < 2; ++kk) {
        const float* p = p0 + atl * 1024 + kk * 32;
        buf[(atl * 2 + kk) * 2 + 0] = reinterpret_cast<const float4*>(p)[0];
        buf[(atl * 2 + kk) * 2 + 1] = reinterpret_cast<const float4*>(p)[1];
      }
  };

  issue(xa, 0);
  issue(xb, 1);

#pragma unroll
  for (int r = 0; r < ROWS; ++r) {
    // ---------------- Stage 1: C1 = Xm * B^T (two halves) ----------------
#pragma unroll
    for (int h = 0; h < 2; ++h) {
      const int H = 2 * r + h;
      float4* cur = (H & 1) ? xb : xa;
#pragma unroll
      for (int atl = 0; atl < 2; ++atl) {
        const int at = 2 * h + atl;
        float4v acc[4];
#pragma unroll
        for (int qt = 0; qt < 4; ++qt) acc[qt] = vzero;
#pragma unroll
        for (int kk = 0; kk < 2; ++kk) {
          short8v xf = cvt8(cur[(atl * 2 + kk) * 2], cur[(atl * 2 + kk) * 2 + 1]);
#pragma unroll
          for (int qt = 0; qt < 4; ++qt)
            acc[qt] = __builtin_amdgcn_mfma_f32_16x16x32_bf16(
                xf, bfr[qt][kk], acc[qt], 0, 0, 0);
        }
        // lane holds C1[16at+4g+b][16qt+c]; store transposed, swizzled
#pragma unroll
        for (int qt = 0; qt < 4; ++qt) {
          short4v v;
          v[0] = f2bf(acc[qt][0]); v[1] = f2bf(acc[qt][1]);
          v[2] = f2bf(acc[qt][2]); v[3] = f2bf(acc[qt][3]);
          int idx = ((16 * qt + c) * 64 + 16 * at + 4 * g) ^ swz;
          *reinterpret_cast<short4v*>(&yw[idx]) = v;
        }
      }
      // buffer consumed -> refill with half H+2 (stays in flight thru stage 2)
      if (H + 2 < 2 * ROWS) issue(cur, H + 2);
    }

    // -------- Stage 2: C2^T = Y1^T * A^T (q-halves to cap liveness) --------
    float* om = out + (size_t)(m0 + r) * 4096;
#pragma unroll
    for (int qh = 0; qh < 2; ++qh) {
      short8v yfr[2][2];  // frag(qtl,kk)[i] = Y1T[16(2qh+qtl)+c][32kk+8g+i]
#pragma unroll
      for (int qtl = 0; qtl < 2; ++qtl)
#pragma unroll
        for (int kk = 0; kk < 2; ++kk) {
          int idx = ((16 * (2 * qh + qtl) + c) * 64) + ((32 * kk + 8 * g) ^ swz);
          yfr[qtl][kk] = *reinterpret_cast<const short8v*>(&yw[idx]);
        }
#pragma unroll
      for (int pt = 0; pt < 4; ++pt) {
        short8v afr[2];  // frag(kk)[i] = A[16pt+c][32kk+8g+i]
#pragma unroll
        for (int kk = 0; kk < 2; ++kk)
          afr[kk] = *reinterpret_cast<const short8v*>(
              &aw[(16 * pt + c) * 64 + ((32 * kk + 8 * g) ^ swz)]);
#pragma unroll
        for (int qtl = 0; qtl < 2; ++qtl) {
          // lane holds C2[p=16pt+c][q=16(2qh+qtl)+4g+b] -> n = p*64+q
          const int n = (16 * pt + c) * 64 + 16 * (2 * qh + qtl) + 4 * g;
          float4 bv = *reinterpret_cast<const float4*>(bias + n);
          float4v acc; acc[0] = bv.x; acc[1] = bv.y; acc[2] = bv.z; acc[3] = bv.w;
#pragma unroll
          for (int kk = 0; kk < 2; ++kk)
            acc = __builtin_amdgcn_mfma_f32_16x16x32_bf16(
                yfr[qtl][kk], afr[kk], acc, 0, 0, 0);
          *reinterpret_cast<float4v*>(om + n) = acc;
        }
      }
    }
  }
}

extern "C" void kernel_launch(void* const* d_in, const int* in_sizes, int n_in,
                              void* d_out, int out_size, void* d_ws, size_t ws_size,
                              hipStream_t stream) {
  (void)in_sizes; (void)n_in; (void)out_size; (void)d_ws; (void)ws_size;
  const float* x    = (const float*)d_in[0];
  const float* A    = (const float*)d_in[1];
  const float* B    = (const float*)d_in[2];
  const float* bias = (const float*)d_in[3];
  float* out = (float*)d_out;

  dim3 grid(512), block(256);
  hipLaunchKernelGGL(kron64_kernel, grid, block, 0, stream, x, A, B, bias, out);
}

// Round 9
// 60.711 us; speedup vs baseline: 1.2993x; 1.2993x over previous
//
#include <hip/hip_runtime.h>

typedef __attribute__((ext_vector_type(8))) short short8v;
typedef __attribute__((ext_vector_type(4))) short short4v;
typedef __attribute__((ext_vector_type(4))) float float4v;

// fp32 -> bf16 via native cast: compiler emits v_cvt_pk_bf16_f32 (RNE).
__device__ __forceinline__ short f2bf(float f) {
  __bf16 h = (__bf16)f;
  return __builtin_bit_cast(short, h);
}

__device__ __forceinline__ short8v cvt8(float4 a, float4 b) {
  short8v r;
  r[0] = f2bf(a.x); r[1] = f2bf(a.y); r[2] = f2bf(a.z); r[3] = f2bf(a.w);
  r[4] = f2bf(b.x); r[5] = f2bf(b.y); r[6] = f2bf(b.z); r[7] = f2bf(b.w);
  return r;
}

// Stage a 64x64 f32 matrix into LDS as bf16, XOR-swizzled:
// element (r, col) -> dst[r*64 + (col ^ ((r&7)<<3))].
__device__ __forceinline__ void stage_weight(const float* __restrict__ src,
                                             short* __restrict__ dst, int tid) {
  const int r = tid >> 2;
  const int c0 = (tid & 3) << 4;
  const float* p = src + r * 64 + c0;
  float4 f0 = reinterpret_cast<const float4*>(p)[0];
  float4 f1 = reinterpret_cast<const float4*>(p)[1];
  float4 f2 = reinterpret_cast<const float4*>(p)[2];
  float4 f3 = reinterpret_cast<const float4*>(p)[3];
  short8v g0 = cvt8(f0, f1), g1 = cvt8(f2, f3);
  const int sw = (r & 7) << 3;
  *reinterpret_cast<short8v*>(&dst[r * 64 + ((c0)     ^ sw)]) = g0;
  *reinterpret_cast<short8v*>(&dst[r * 64 + ((c0 + 8) ^ sw)]) = g1;
}

constexpr int ROWS = 2;  // rows per wave; grid = 8192/(4*ROWS) = 1024

// Spill-safe MLP pipeline (R8 post-mortem: same idea spilled at 144-est
// liveness under the 128 cap and ran at 21% occupancy from grid=512).
// Fixes: ROWS=2 + grid=1024 (12 waves/CU via 3 blocks/CU at 48 KB LDS),
// and NO persistent weight fragments — B/A frags are re-read from LDS at
// each use so the register peak is bufs(64)+acc(16)+transients(~30) < 128.
// Fenceless y1 write->read ordering validated by R8 (in-order per-wave DS
// pipe + may-alias compiler ordering). Next row's 16 dwordx4 are issued
// right after each buffer is consumed and stay in flight through stage 2.
__global__ __launch_bounds__(256, 2)
void kron64_kernel(const float* __restrict__ x, const float* __restrict__ A,
                   const float* __restrict__ B, const float* __restrict__ bias,
                   float* __restrict__ out) {
  __shared__ short bw[4096];     // B bf16 [64][64] swizzled, 8 KB
  __shared__ short aw[4096];     // A bf16 [64][64] swizzled, 8 KB
  __shared__ short y1[4][4096];  // per-wave Y1^T, 32 KB

  const int tid = threadIdx.x;
  const int w = tid >> 6;
  const int lane = tid & 63;
  const int g = lane >> 4;       // lane group 0..3
  const int c = lane & 15;       // lane-in-group 0..15
  const int swz = (c & 7) << 3;  // element-index XOR swizzle (row&7 == c&7)

  stage_weight(B, bw, tid);
  stage_weight(A, aw, tid);
  __syncthreads();

  const int m0 = (blockIdx.x * 4 + w) * ROWS;
  const float* xm = x + (size_t)m0 * 4096;
  short* yw = y1[w];
  const float4v vzero = {0.f, 0.f, 0.f, 0.f};

  float4 bufA[8], bufB[8];  // two half-row buffers, 32 VGPR each

  // Half H (= 2*row + h) covers at in {2h, 2h+1}: 8 dwordx4.
  auto issue = [&](float4* buf, int H) {
    const float* p0 =
        xm + (size_t)(H >> 1) * 4096 + ((H & 1) * 32 + c) * 64 + 8 * g;
#pragma unroll
    for (int atl = 0; atl < 2; ++atl)
#pragma unroll
      for (int kk = 0; kk < 2; ++kk) {
        const float* p = p0 + atl * 1024 + kk * 32;
        buf[(atl * 2 + kk) * 2 + 0] = reinterpret_cast<const float4*>(p)[0];
        buf[(atl * 2 + kk) * 2 + 1] = reinterpret_cast<const float4*>(p)[1];
      }
  };

  // Stage-1 on one half-row buffer: at in {2h, 2h+1}. B-frags are read
  // from LDS at use (transient 8 regs), not held persistently.
  auto s1half = [&](const float4* cur, int h) {
#pragma unroll
    for (int atl = 0; atl < 2; ++atl) {
      const int at = 2 * h + atl;
      float4v acc[4];
#pragma unroll
      for (int qt = 0; qt < 4; ++qt) acc[qt] = vzero;
#pragma unroll
      for (int kk = 0; kk < 2; ++kk) {
        short8v xf = cvt8(cur[(atl * 2 + kk) * 2], cur[(atl * 2 + kk) * 2 + 1]);
#pragma unroll
        for (int qt = 0; qt < 4; ++qt) {
          short8v bfrk = *reinterpret_cast<const short8v*>(
              &bw[(16 * qt + c) * 64 + ((32 * kk + 8 * g) ^ swz)]);
          acc[qt] = __builtin_amdgcn_mfma_f32_16x16x32_bf16(
              xf, bfrk, acc[qt], 0, 0, 0);
        }
      }
      // lane holds C1[16at+4g+b][16qt+c]; store transposed, swizzled
#pragma unroll
      for (int qt = 0; qt < 4; ++qt) {
        short4v v;
        v[0] = f2bf(acc[qt][0]); v[1] = f2bf(acc[qt][1]);
        v[2] = f2bf(acc[qt][2]); v[3] = f2bf(acc[qt][3]);
        int idx = ((16 * qt + c) * 64 + 16 * at + 4 * g) ^ swz;
        *reinterpret_cast<short4v*>(&yw[idx]) = v;
      }
    }
  };

  issue(bufA, 0);
  issue(bufB, 1);

#pragma unroll
  for (int r = 0; r < ROWS; ++r) {
    s1half(bufA, 0);
    if (r + 1 < ROWS) issue(bufA, 2 * (r + 1) + 0);  // in flight thru s2
    s1half(bufB, 1);
    if (r + 1 < ROWS) issue(bufB, 2 * (r + 1) + 1);  // in flight thru s2

    // -------- Stage 2: C2^T = Y1^T * A^T (q-halves to cap liveness) --------
    float* om = out + (size_t)(m0 + r) * 4096;
#pragma unroll
    for (int qh = 0; qh < 2; ++qh) {
      short8v yfr[2][2];  // frag(qtl,kk)[i] = Y1T[16(2qh+qtl)+c][32kk+8g+i]
#pragma unroll
      for (int qtl = 0; qtl < 2; ++qtl)
#pragma unroll
        for (int kk = 0; kk < 2; ++kk) {
          int idx = ((16 * (2 * qh + qtl) + c) * 64) + ((32 * kk + 8 * g) ^ swz);
          yfr[qtl][kk] = *reinterpret_cast<const short8v*>(&yw[idx]);
        }
#pragma unroll
      for (int pt = 0; pt < 4; ++pt) {
#pragma unroll
        for (int qtl = 0; qtl < 2; ++qtl) {
          // lane holds C2[p=16pt+c][q=16(2qh+qtl)+4g+b] -> n = p*64+q
          const int n = (16 * pt + c) * 64 + 16 * (2 * qh + qtl) + 4 * g;
          float4 bv = *reinterpret_cast<const float4*>(bias + n);
          float4v acc; acc[0] = bv.x; acc[1] = bv.y; acc[2] = bv.z; acc[3] = bv.w;
#pragma unroll
          for (int kk = 0; kk < 2; ++kk) {
            short8v afrk = *reinterpret_cast<const short8v*>(
                &aw[(16 * pt + c) * 64 + ((32 * kk + 8 * g) ^ swz)]);
            acc = __builtin_amdgcn_mfma_f32_16x16x32_bf16(
                yfr[qtl][kk], afrk, acc, 0, 0, 0);
          }
          *reinterpret_cast<float4v*>(om + n) = acc;
        }
      }
    }
  }
}

extern "C" void kernel_launch(void* const* d_in, const int* in_sizes, int n_in,
                              void* d_out, int out_size, void* d_ws, size_t ws_size,
                              hipStream_t stream) {
  (void)in_sizes; (void)n_in; (void)out_size; (void)d_ws; (void)ws_size;
  const float* x    = (const float*)d_in[0];
  const float* A    = (const float*)d_in[1];
  const float* B    = (const float*)d_in[2];
  const float* bias = (const float*)d_in[3];
  float* out = (float*)d_out;

  dim3 grid(1024), block(256);
  hipLaunchKernelGGL(kron64_kernel, grid, block, 0, stream, x, A, B, bias, out);
}

// Round 10
// 55.454 us; speedup vs baseline: 1.4224x; 1.0948x over previous
//
#include <hip/hip_runtime.h>

typedef __attribute__((ext_vector_type(8))) short short8v;
typedef __attribute__((ext_vector_type(4))) short short4v;
typedef __attribute__((ext_vector_type(4))) float float4v;

// fp32 -> bf16 via native cast: compiler emits v_cvt_pk_bf16_f32 (RNE).
__device__ __forceinline__ short f2bf(float f) {
  __bf16 h = (__bf16)f;
  return __builtin_bit_cast(short, h);
}

__device__ __forceinline__ short8v cvt8(float4 a, float4 b) {
  short8v r;
  r[0] = f2bf(a.x); r[1] = f2bf(a.y); r[2] = f2bf(a.z); r[3] = f2bf(a.w);
  r[4] = f2bf(b.x); r[5] = f2bf(b.y); r[6] = f2bf(b.z); r[7] = f2bf(b.w);
  return r;
}

// Stage a 64x64 f32 matrix into LDS as bf16, XOR-swizzled:
// element (r, col) -> dst[r*64 + (col ^ ((r&7)<<3))].
__device__ __forceinline__ void stage_weight(const float* __restrict__ src,
                                             short* __restrict__ dst, int tid) {
  const int r = tid >> 2;
  const int c0 = (tid & 3) << 4;
  const float* p = src + r * 64 + c0;
  float4 f0 = reinterpret_cast<const float4*>(p)[0];
  float4 f1 = reinterpret_cast<const float4*>(p)[1];
  float4 f2 = reinterpret_cast<const float4*>(p)[2];
  float4 f3 = reinterpret_cast<const float4*>(p)[3];
  short8v g0 = cvt8(f0, f1), g1 = cvt8(f2, f3);
  const int sw = (r & 7) << 3;
  *reinterpret_cast<short8v*>(&dst[r * 64 + ((c0)     ^ sw)]) = g0;
  *reinterpret_cast<short8v*>(&dst[r * 64 + ((c0 + 8) ^ sw)]) = g1;
}

// Half-row-per-wave block-cooperative version (R9 post-mortem: per-wave
// efficiency x wave-count pins at ~3.5 TB/s; remaining suspect is stall
// granularity — 64-VGPR waves couldn't hoist x loads, stalling every ~2
// loads). Block (4 waves) = 2 rows; wave (w>>1 = row, w&1 = a-half) hoists
// ALL 8 of its x dwordx4 up-front (32 VGPR), computes stage-1 for its
// a-half into the row-shared y1, one __syncthreads, then stage-2 for its
// q-half. Waves are short and lean (est. ~90 VGPR under a safe 128 cap):
// 4 blocks/CU = 16 waves/CU, 16 block-generations over the grid.
__global__ __launch_bounds__(256, 4)
void kron64_kernel(const float* __restrict__ x, const float* __restrict__ A,
                   const float* __restrict__ B, const float* __restrict__ bias,
                   float* __restrict__ out) {
  __shared__ short bw[4096];     // B bf16 [64][64] swizzled, 8 KB
  __shared__ short aw[4096];     // A bf16 [64][64] swizzled, 8 KB
  __shared__ short y1[2][4096];  // per-ROW Y1^T (64q x 64a bf16), 16 KB

  const int tid = threadIdx.x;
  const int w = tid >> 6;
  const int lane = tid & 63;
  const int g = lane >> 4;       // lane group 0..3
  const int c = lane & 15;       // lane-in-group 0..15
  const int swz = (c & 7) << 3;  // element-index XOR swizzle (row&7 == c&7)

  stage_weight(B, bw, tid);
  stage_weight(A, aw, tid);

  const int rs = w >> 1;         // row slot in block (0,1)
  const int half = w & 1;        // a-half (stage 1) / q-half (stage 2)
  const int m = blockIdx.x * 2 + rs;
  const float* xm = x + (size_t)m * 4096;
  short* yw = y1[rs];
  const float4v vzero = {0.f, 0.f, 0.f, 0.f};

  // ---- hoist ALL x loads for this wave's a-half: 8 dwordx4, 32 VGPR ----
  const int A0 = 2 * half;  // at in {A0, A0+1}
  float4 xb[8];
  {
    const float* base = xm + (16 * A0 + c) * 64 + 8 * g;
#pragma unroll
    for (int atl = 0; atl < 2; ++atl)
#pragma unroll
      for (int kk = 0; kk < 2; ++kk) {
        const float* p = base + atl * 1024 + kk * 32;
        xb[(atl * 2 + kk) * 2 + 0] = reinterpret_cast<const float4*>(p)[0];
        xb[(atl * 2 + kk) * 2 + 1] = reinterpret_cast<const float4*>(p)[1];
      }
  }

  __syncthreads();  // weights staged (x loads above remain in flight)

  // ---------------- Stage 1: C1[a-half] = Xm_half * B^T ----------------
#pragma unroll
  for (int atl = 0; atl < 2; ++atl) {
    const int at = A0 + atl;
    float4v acc[4];
#pragma unroll
    for (int qt = 0; qt < 4; ++qt) acc[qt] = vzero;
#pragma unroll
    for (int kk = 0; kk < 2; ++kk) {
      short8v xf = cvt8(xb[(atl * 2 + kk) * 2], xb[(atl * 2 + kk) * 2 + 1]);
#pragma unroll
      for (int qt = 0; qt < 4; ++qt) {
        short8v bfrk = *reinterpret_cast<const short8v*>(
            &bw[(16 * qt + c) * 64 + ((32 * kk + 8 * g) ^ swz)]);
        acc[qt] = __builtin_amdgcn_mfma_f32_16x16x32_bf16(
            xf, bfrk, acc[qt], 0, 0, 0);
      }
    }
    // lane holds C1[16at+4g+b][16qt+c]; store transposed Y1T[q][a], swizzled
#pragma unroll
    for (int qt = 0; qt < 4; ++qt) {
      short4v v;
      v[0] = f2bf(acc[qt][0]); v[1] = f2bf(acc[qt][1]);
      v[2] = f2bf(acc[qt][2]); v[3] = f2bf(acc[qt][3]);
      int idx = ((16 * qt + c) * 64 + 16 * at + 4 * g) ^ swz;
      *reinterpret_cast<short4v*>(&yw[idx]) = v;
    }
  }

  __syncthreads();  // both a-halves of each row's y1 complete

  // ---------------- Stage 2: C2^T[q-half] = Y1^T * A^T ----------------
  {
    short8v yfr[2][2];  // frag(qtl,kk): Y1T[16(2*half+qtl)+c][32kk+8g+i]
#pragma unroll
    for (int qtl = 0; qtl < 2; ++qtl)
#pragma unroll
      for (int kk = 0; kk < 2; ++kk) {
        int idx = ((16 * (2 * half + qtl) + c) * 64) + ((32 * kk + 8 * g) ^ swz);
        yfr[qtl][kk] = *reinterpret_cast<const short8v*>(&yw[idx]);
      }

    float* om = out + (size_t)m * 4096;
#pragma unroll
    for (int pt = 0; pt < 4; ++pt) {
      short8v afr[2];  // frag(kk): A[16pt+c][32kk+8g+i]
#pragma unroll
      for (int kk = 0; kk < 2; ++kk)
        afr[kk] = *reinterpret_cast<const short8v*>(
            &aw[(16 * pt + c) * 64 + ((32 * kk + 8 * g) ^ swz)]);
#pragma unroll
      for (int qtl = 0; qtl < 2; ++qtl) {
        // lane holds C2[p=16pt+c][q=16(2*half+qtl)+4g+b] -> n = p*64+q
        const int n = (16 * pt + c) * 64 + 16 * (2 * half + qtl) + 4 * g;
        float4 bv = *reinterpret_cast<const float4*>(bias + n);
        float4v acc; acc[0] = bv.x; acc[1] = bv.y; acc[2] = bv.z; acc[3] = bv.w;
#pragma unroll
        for (int kk = 0; kk < 2; ++kk)
          acc = __builtin_amdgcn_mfma_f32_16x16x32_bf16(
              yfr[qtl][kk], afr[kk], acc, 0, 0, 0);
        *reinterpret_cast<float4v*>(om + n) = acc;
      }
    }
  }
}

extern "C" void kernel_launch(void* const* d_in, const int* in_sizes, int n_in,
                              void* d_out, int out_size, void* d_ws, size_t ws_size,
                              hipStream_t stream) {
  (void)in_sizes; (void)n_in; (void)out_size; (void)d_ws; (void)ws_size;
  const float* x    = (const float*)d_in[0];
  const float* A    = (const float*)d_in[1];
  const float* B    = (const float*)d_in[2];
  const float* bias = (const float*)d_in[3];
  float* out = (float*)d_out;

  dim3 grid(4096), block(256);
  hipLaunchKernelGGL(kron64_kernel, grid, block, 0, stream, x, A, B, bias, out);
}